// Round 7
// baseline (167.119 us; speedup 1.0000x reference)
//
#include <hip/hip_runtime.h>
#include <stdint.h>

// SpottingLoss: B=2048 batches, N=64 slots, F=19 features.
// Two-phase greedy bipartite matching (lax.scan, length 64 each) then
// permuted YOLO-ish loss summed over ALL axes -> single float output.
//
// Exactness argument (verified absmax 0.0 in rounds 0-6):
//  - alpha in {0,1}; v,h stay {0,1}; D2 = D1 * (0/1 masks), so masking D1
//    (fp32, 1-|x-p|, bit-identical) by the live-column bitmask reproduces
//    D2 bitwise. x,p ~ U[0,1): D1 > 0 strictly, so every live row always
//    has a positive live candidate (live cols >= live rows) -> the
//    reference's "best>0" guard is vacuous and the u64 key of any live
//    column ( (val_bits<<6)|(63-j), val_bits>=1 ) always beats any
//    masked-out column's key (<=63).
//  - Row argmax first-index ties: serial chain 'kj > bk ? kj : bk' with
//    key (masked_val_bits<<6)|(63-j): equal vals -> larger 63-j = smaller
//    j wins; later j never displaces equal earlier j. Bitwise = reference.
//  - Column argmax: key (val_bits<<6)|(63-row) via LDS atomicMax: monotone
//    in val (val>0), larger 63-row = smaller row = first index.
//  - Every column proposed by a live row is matched to its best proposer
//    IN THAT ROUND (Bm = v*A*D2 is nonzero exactly at proposers; C picks
//    the max; E=v*A*C=1 there), so proposed columns always die -> a loser
//    always rescans (no killed>>jmax check needed), and the no-reset key
//    protocol is valid: live columns have never been written this batch
//    (init 63 once per batch); stale keys on dead columns only re-assert
//    kills, and hbits &= ~killed is idempotent.
//  - Dead rows only contribute zeros downstream; early exit when
//    ballot(vlive)==0: remaining scan steps are no-ops (E==0). Unmatched
//    rows keep perm=0 == argmax of an all-zero Permut row.
//  - Wave-local WSYNC (s_waitcnt lgkmcnt(0)) replaces __syncthreads
//    (validated rounds 4-6): all ordering consumers are this wave's own
//    ds ops; one wave's DS ops are processed in issue order.
//
// Round-7 theory: R0-R6 established wall = threads/2520us + tail:
// R0-4,6: 131072 thr / 52us = 2520 thr/us; R5: 65536/(76-50tail) = 2520.
// The wall was a WAVE-LAUNCH throughput ceiling (~25ns/wave, ~39.4
// waves/us) -- kernel content was invisible under it (VALU+70%, atomics,
// memory pattern, WG shape: all null). Fix: 512 waves (ramp ~13us), each
// popping batches dynamically from a global atomic counter (balances
// launch skew); per-batch life slimmed (register key-chain argmax, 1 LDS
// drain + 2 reads per round, yt unstaged). Predicted dispatch ~20us.

#define NN 64
#define NF 19
#define NW (NN * NF)   // 1216 floats per (batch, tensor)
#define NW4 (NW / 4)   // 304 float4
#define WPB 4          // waves per workgroup
#define NWG 128        // workgroups -> 512 waves total
typedef unsigned long long u64;

// Wave-local LDS ordering: prior ds ops (writes/atomics) by this wave are
// complete and visible to this wave's subsequent ds reads.
#define WSYNC() asm volatile("s_waitcnt lgkmcnt(0)" ::: "memory")

__global__ __launch_bounds__(WPB * 64, 1) void spotting_loss_kernel(
    const float* __restrict__ yt, const float* __restrict__ yp,
    float* __restrict__ ws, unsigned* __restrict__ ctr, int nbatch)
{
  const int wid = threadIdx.x >> 6;   // wave id in block
  const int i   = threadIdx.x & 63;   // lane = row index
  const int g   = blockIdx.x * WPB + wid;  // global wave id 0..511

  __shared__ float4 yps4[WPB][NW4];
  __shared__ u64 key_lds[WPB][NN];
  const float* __restrict__ yps = (const float*)&yps4[wid][0];
  u64* __restrict__ key_sh = &key_lds[wid][0];

  float lsum = 0.0f;

#pragma unroll 1
  for (;;) {
    // one lane pops the next batch index; broadcast to the wave
    unsigned bb;
    if (i == 0) bb = atomicAdd(ctr, 1u);
    bb = (unsigned)__shfl((int)bb, 0);
    if (bb >= (unsigned)nbatch) break;
    const int b = (int)bb;

    // stage this batch's yp rows into this wave's LDS slice (reused 64x+);
    // yt is read-once -> straight from global.
    const float4* __restrict__ yp4 = (const float4*)(yp + (size_t)b * NW);
#pragma unroll
    for (int k = 0; k < 5; ++k) {
      const int idx = i + 64 * k;     // 304 = 4*64 + 48
      if (idx < NW4) yps4[wid][idx] = yp4[idx];
    }
    key_sh[i] = 63ull;  // per-batch init: (val=0,row=0); never reset again
    const float* __restrict__ ytr = yt + (size_t)b * NW + (size_t)i * NF;
    const float alpha = ytr[0];
    const float x     = ytr[1];
    WSYNC();

    // D1 row -> registers, pinned so the compiler cannot rematerialize
    // from LDS inside every rescan (R6: it did exactly that at VGPR=52).
    float D1r[NN];
#pragma unroll
    for (int j = 0; j < NN; ++j) {
      D1r[j] = 1.0f - fabsf(x - yps[j * NF + 1]);
      asm volatile("" : "+v"(D1r[j]));
    }

    u64 hbits = ~0ull;  // column j alive <=> bit j set
    int perm  = 0;      // matched column (argmax of zero row -> 0)

#pragma unroll 1
    for (int phase = 0; phase < 2; ++phase) {
      bool vlive  = (phase == 0) ? (alpha > 0.5f) : (alpha < 0.5f);
      bool rescan = vlive;
      u64  bk     = 0;  // (best_val_bits<<6)|(63-jmax)
      int  jmax   = 0;

#pragma unroll 1
      for (int it = 0; it < NN; ++it) {
        if (__ballot(vlive) == 0ull) break;  // remaining steps are no-ops

        if (rescan) {
          // first-index argmax over D1 masked by live columns,
          // pure-register serial u64 key chain (no LDS).
          const unsigned hlo = (unsigned)hbits;
          const unsigned hhi = (unsigned)(hbits >> 32);
          bk = 0;
#pragma unroll
          for (int j = 0; j < NN; ++j) {
            const unsigned bit = (j < 32) ? ((hlo >> j) & 1u)
                                          : ((hhi >> (j - 32)) & 1u);
            const unsigned mv = __float_as_uint(D1r[j]) & (0u - bit);
            const u64 kj = (((u64)mv) << 6) | (u64)(63 - j);
            bk = (kj > bk) ? kj : bk;
          }
          jmax = 63 - (int)(bk & 63ull);
          rescan = false;
        }

        if (vlive) {
          // column key: same val bits, row id in low 6 (first-row ties)
          atomicMax(&key_sh[jmax], (bk & ~63ull) | (u64)(63 - i));
        }
        WSYNC();  // this wave's ds_max ops all complete

        const u64 kc = key_sh[i];     // my column: proposed <=> key>63
        u64 kw = 63ull;
        if (vlive) kw = key_sh[jmax]; // winner of my target column
        // (compiler inserts the lgkmcnt wait before first use)

        const u64 killed = __ballot((kc >> 6) != 0ull);
        if (vlive) {
          if ((int)(kw & 63ull) == 63 - i) {  // mutual match
            perm  = jmax;
            vlive = false;
          } else {
            rescan = true;  // proposed column always dies -> always rescan
          }
        }
        hbits &= ~killed;
      }
    }

    // ----- loss: yp fields from LDS (perm-gather), yt direct global -----
    const float* __restrict__ ypr = yps + perm * NF;
    const float a  = alpha;
    const float p0 = ypr[0];
    const float p1 = ypr[1];
    const float dx = x - p1;
    const float da = a - p0;
    float s2 = 0.0f;
#pragma unroll
    for (int f = 2; f < NF; ++f) {
      const float d = ytr[f] - ypr[f];
      s2 += d * d;
    }
    lsum += a * 5.0f * (dx * dx)
          + a * (da * da)
          + (1.0f - a) * 0.5f * (da * da)
          + a * s2;
  }

  // wave-64 reduction of this wave's accumulated partials, one store/wave
#pragma unroll
  for (int off = 32; off > 0; off >>= 1) lsum += __shfl_down(lsum, off);
  if (i == 0) ws[g] = lsum;
}

__global__ __launch_bounds__(256) void reduce_ws_kernel(
    const float* __restrict__ ws, float* __restrict__ out, int nw)
{
  const int t = threadIdx.x;
  float s = 0.0f;
  for (int j = t; j < nw; j += 256) s += ws[j];
  __shared__ float part[4];
#pragma unroll
  for (int off = 32; off > 0; off >>= 1) s += __shfl_down(s, off);
  if ((t & 63) == 0) part[t >> 6] = s;
  __syncthreads();
  if (t == 0) out[0] = part[0] + part[1] + part[2] + part[3];
}

extern "C" void kernel_launch(void* const* d_in, const int* in_sizes, int n_in,
                              void* d_out, int out_size, void* d_ws, size_t ws_size,
                              hipStream_t stream) {
  const float* yt = (const float*)d_in[0];
  const float* yp = (const float*)d_in[1];
  float* out = (float*)d_out;
  float* ws  = (float*)d_ws;
  const int B = in_sizes[0] / (NN * NF);
  const int nwaves = NWG * WPB;  // 512

  // ws layout: [0, nwaves) partial sums; counter at ws[nwaves] (4B)
  unsigned* ctr = (unsigned*)(ws + nwaves);
  hipMemsetAsync(ctr, 0, sizeof(unsigned), stream);
  if (out_size > 1) {
    hipMemsetAsync(out, 0, sizeof(float) * (size_t)out_size, stream);
  }
  spotting_loss_kernel<<<NWG, WPB * 64, 0, stream>>>(yt, yp, ws, ctr, B);
  reduce_ws_kernel<<<1, 256, 0, stream>>>(ws, out, nwaves);
}